// Round 8
// baseline (972.268 us; speedup 1.0000x reference)
//
#include <hip/hip_runtime.h>

#define NSEG 4096
#define QSCALE 131072.0f          // 2^17 fixed-point scale
#define QINV   (1.0f / 131072.0f)
#define NB 512                    // reduce blocks (= partial count)

typedef unsigned long long u64;
typedef unsigned int u32;
typedef float f32x4 __attribute__((ext_vector_type(4)));
typedef float f32x2 __attribute__((ext_vector_type(2)));

// ---------------------------------------------------------------------------
// Pass 1: per-segment exp-sums. Split across two pipes:
//   - xab/src: u64 fixed-point atomics into LDS (DS pipe), flushed to
//     per-block partial tables.
//   - xba/tar: u64 fixed-point atomics directly into a 32 KB global table
//     (L2 atomic pipe) — runs concurrently with the DS-pipe atomics.
// ---------------------------------------------------------------------------
__global__ __launch_bounds__(1024) void dsp_reduce(
    const f32x4* __restrict__ xab4, const f32x4* __restrict__ xba4,
    const int2* __restrict__ src2, const int2* __restrict__ tar2,
    float* __restrict__ partials,   // [NB][8192] floats (ab only), or nullptr
    u64* __restrict__ gab,          // fallback: global u64 table for ab
    u64* __restrict__ gba,          // global u64 table for ba (always)
    int Eh)
{
    __shared__ u64 ls[NSEG];        // ab table only: 32 KB
    for (int i = threadIdx.x; i < NSEG; i += 1024) ls[i] = 0ull;
    __syncthreads();

    const int stride = gridDim.x * 1024;
    for (int u = blockIdx.x * 1024 + threadIdx.x; u < Eh; u += stride) {
        f32x4 a = xab4[u];           // edges 2u, 2u+1 (ch0,ch1 each)
        f32x4 b = xba4[u];
        int2 s = src2[u];
        int2 t = tar2[u];

        u32 b0 = __float2uint_rn(__expf(b.x) * QSCALE);
        u32 b1 = __float2uint_rn(__expf(b.y) * QSCALE);
        u32 b2 = __float2uint_rn(__expf(b.z) * QSCALE);
        u32 b3 = __float2uint_rn(__expf(b.w) * QSCALE);
        atomicAdd(&gba[t.x], (u64)b0 | ((u64)b1 << 32));   // L2 pipe
        atomicAdd(&gba[t.y], (u64)b2 | ((u64)b3 << 32));

        u32 a0 = __float2uint_rn(__expf(a.x) * QSCALE);
        u32 a1 = __float2uint_rn(__expf(a.y) * QSCALE);
        u32 a2 = __float2uint_rn(__expf(a.z) * QSCALE);
        u32 a3 = __float2uint_rn(__expf(a.w) * QSCALE);
        if (partials) {
            atomicAdd(&ls[s.x], (u64)a0 | ((u64)a1 << 32));  // DS pipe
            atomicAdd(&ls[s.y], (u64)a2 | ((u64)a3 << 32));
        } else {
            atomicAdd(&gab[s.x], (u64)a0 | ((u64)a1 << 32));
            atomicAdd(&gab[s.y], (u64)a2 | ((u64)a3 << 32));
        }
    }
    __syncthreads();

    if (partials) {
        // flush ab partial table: 8192 floats, layout [2*seg+ch]
        f32x2* dst = (f32x2*)(partials + (size_t)blockIdx.x * (2 * NSEG));
        for (int i = threadIdx.x; i < NSEG; i += 1024) {
            u64 v = ls[i];
            f32x2 w = { (float)(u32)v * QINV, (float)(u32)(v >> 32) * QINV };
            dst[i] = w;
        }
    }
}

// ---------------------------------------------------------------------------
// Pass 2a: ab — column-sum NB partial tables, store reciprocals into
// rcp_tab[0..8192). 2048 f32x4 columns.
// ---------------------------------------------------------------------------
__global__ __launch_bounds__(256) void dsp_sum_ab(
    const f32x4* __restrict__ partials, f32x4* __restrict__ rcp_ab, int nb)
{
    int i = blockIdx.x * blockDim.x + threadIdx.x;   // 0..2047
    f32x4 acc = {0.f, 0.f, 0.f, 0.f};
    for (int p = 0; p < nb; ++p)
        acc += partials[(size_t)p * (NSEG / 2) + i];
    f32x4 r;
    r.x = (acc.x > 0.f) ? 1.f / acc.x : 0.f;
    r.y = (acc.y > 0.f) ? 1.f / acc.y : 0.f;
    r.z = (acc.z > 0.f) ? 1.f / acc.z : 0.f;
    r.w = (acc.w > 0.f) ? 1.f / acc.w : 0.f;
    rcp_ab[i] = r;
}

// ---------------------------------------------------------------------------
// Pass 2b: ba — decode global u64 table, store reciprocals into
// rcp_tab[8192..16384). (Also used for ab in the no-partials fallback.)
// ---------------------------------------------------------------------------
__global__ __launch_bounds__(256) void dsp_sum_u64(
    const u64* __restrict__ gtab, f32x2* __restrict__ rcp_out)
{
    int j = blockIdx.x * blockDim.x + threadIdx.x;   // 0..4095
    u64 v = gtab[j];
    float lo = (float)(u32)v * QINV;
    float hi = (float)(u32)(v >> 32) * QINV;
    f32x2 r = { (lo > 0.f) ? 1.f / lo : 0.f,
                (hi > 0.f) ? 1.f / hi : 0.f };
    rcp_out[j] = r;
}

// ---------------------------------------------------------------------------
// Pass 3: normalize + write 3 outputs. rcp tables staged in LDS (64 KB),
// pipelined grid-stride, NT stores.
// LDS float layout: ab at [0,2*NSEG), ba at [2*NSEG,4*NSEG).
// ---------------------------------------------------------------------------
__global__ __launch_bounds__(1024) void dsp_norm(
    const f32x4* __restrict__ xab4, const f32x4* __restrict__ xba4,
    const int2* __restrict__ src2, const int2* __restrict__ tar2,
    const f32x4* __restrict__ rcp_tab,
    f32x4* __restrict__ out, int Eh)
{
    __shared__ float ls[4 * NSEG];
    for (int i = threadIdx.x; i < NSEG; i += 1024)
        ((f32x4*)ls)[i] = rcp_tab[i];
    __syncthreads();

    const int stride = gridDim.x * 1024;
    int u = blockIdx.x * 1024 + threadIdx.x;

    f32x4 a, b; int2 s, t;
    if (u < Eh) { a = xab4[u]; b = xba4[u]; s = src2[u]; t = tar2[u]; }

    while (u < Eh) {
        int un = u + stride;
        f32x4 an, bn; int2 sn, tn;
        if (un < Eh) { an = xab4[un]; bn = xba4[un]; sn = src2[un]; tn = tar2[un]; }

        f32x2 ra0 = *(const f32x2*)&ls[2 * s.x];
        f32x2 ra1 = *(const f32x2*)&ls[2 * s.y];
        f32x2 rb0 = *(const f32x2*)&ls[2 * NSEG + 2 * t.x];
        f32x2 rb1 = *(const f32x2*)&ls[2 * NSEG + 2 * t.y];

        f32x4 zab = { __expf(a.x) * ra0.x, __expf(a.y) * ra0.y,
                      __expf(a.z) * ra1.x, __expf(a.w) * ra1.y };
        f32x4 zba = { __expf(b.x) * rb0.x, __expf(b.y) * rb0.y,
                      __expf(b.z) * rb1.x, __expf(b.w) * rb1.y };
        f32x4 prod = zab * zba;

        __builtin_nontemporal_store(prod, &out[u]);            // zab*zba
        __builtin_nontemporal_store(zab,  &out[Eh + u]);       // zab
        __builtin_nontemporal_store(zba,  &out[2 * Eh + u]);   // zba

        u = un; a = an; b = bn; s = sn; t = tn;
    }
}

extern "C" void kernel_launch(void* const* d_in, const int* in_sizes, int n_in,
                              void* d_out, int out_size, void* d_ws, size_t ws_size,
                              hipStream_t stream)
{
    const int E  = in_sizes[0] / 2;
    const int Eh = E / 2;
    const f32x4* xab4 = (const f32x4*)d_in[0];
    const f32x4* xba4 = (const f32x4*)d_in[1];
    const int2*  src2 = (const int2*)d_in[2];
    const int2*  tar2 = (const int2*)d_in[3];

    // ws layout: rcp_tab f32[16384] (64KB) | gba u64[4096] (32KB)
    //            | gab u64[4096] (32KB, fallback only) | partials 512*32KB
    float* rcp_tab  = (float*)d_ws;
    u64*   gba      = (u64*)((char*)d_ws + 65536);
    u64*   gab      = (u64*)((char*)d_ws + 65536 + 32768);
    float* partials = (float*)((char*)d_ws + 65536 + 2 * 32768);
    size_t need = 65536 + 2 * 32768 + (size_t)NB * (2 * NSEG) * sizeof(float);

    if (ws_size >= need) {
        (void)hipMemsetAsync(gba, 0, 32768, stream);
        dsp_reduce<<<NB, 1024, 0, stream>>>(xab4, xba4, src2, tar2,
                                            partials, nullptr, gba, Eh);
        dsp_sum_ab<<<(NSEG / 2) / 256, 256, 0, stream>>>(
            (const f32x4*)partials, (f32x4*)rcp_tab, NB);
        dsp_sum_u64<<<NSEG / 256, 256, 0, stream>>>(
            gba, (f32x2*)(rcp_tab + 2 * NSEG));
    } else {
        (void)hipMemsetAsync(gba, 0, 2 * 32768, stream);   // gba + gab
        dsp_reduce<<<NB, 1024, 0, stream>>>(xab4, xba4, src2, tar2,
                                            nullptr, gab, gba, Eh);
        dsp_sum_u64<<<NSEG / 256, 256, 0, stream>>>(
            gab, (f32x2*)rcp_tab);
        dsp_sum_u64<<<NSEG / 256, 256, 0, stream>>>(
            gba, (f32x2*)(rcp_tab + 2 * NSEG));
    }

    dsp_norm<<<NB, 1024, 0, stream>>>(xab4, xba4, src2, tar2,
                                      (const f32x4*)rcp_tab,
                                      (f32x4*)d_out, Eh);
}

// Round 9
// 378.437 us; speedup vs baseline: 2.5692x; 2.5692x over previous
//
#include <hip/hip_runtime.h>

#define NSEG 4096
#define QSCALE 131072.0f          // 2^17 fixed-point scale
#define QINV   (1.0f / 131072.0f)
#define NB 512                    // blocks for reduce/norm (= partial count)

typedef unsigned long long u64;
typedef unsigned int u32;
typedef float f32x4 __attribute__((ext_vector_type(4)));
typedef float f32x2 __attribute__((ext_vector_type(2)));

__device__ __forceinline__ u64 packexp(float x, float y) {
    u32 lo = __float2uint_rn(__expf(x) * QSCALE);
    u32 hi = __float2uint_rn(__expf(y) * QSCALE);
    return (u64)lo | ((u64)hi << 32);
}

// ---------------------------------------------------------------------------
// Pass 1 (exact): per-segment exp-sums, u64 LDS atomics, 4-deep load batching
// (16 independent global loads in flight per wave before the atomic block —
// covers ~900 cy HBM latency with 4 waves/SIMD; R5's 1-deep was too shallow).
// ---------------------------------------------------------------------------
__global__ __launch_bounds__(512, 4) void dsp_reduce_x(
    const f32x4* __restrict__ xab4, const f32x4* __restrict__ xba4,
    const int2* __restrict__ src2, const int2* __restrict__ tar2,
    float* __restrict__ partials,   // [NB][16384] floats
    int groups, int stride)          // stride = NB*512; groups = Eh/(4*stride)
{
    __shared__ u64 ls[2 * NSEG];    // ab at [0,4096), ba at [4096,8192)
    for (int i = threadIdx.x; i < 2 * NSEG; i += 512) ls[i] = 0ull;
    __syncthreads();

    const int base = blockIdx.x * 512 + threadIdx.x;
    for (int g = 0; g < groups; ++g) {
        const int u0 = base + (4 * g) * stride;
        const int u1 = u0 + stride, u2 = u1 + stride, u3 = u2 + stride;

        f32x4 a0 = xab4[u0], a1 = xab4[u1], a2 = xab4[u2], a3 = xab4[u3];
        f32x4 b0 = xba4[u0], b1 = xba4[u1], b2 = xba4[u2], b3 = xba4[u3];
        int2  s0 = src2[u0], s1 = src2[u1], s2 = src2[u2], s3 = src2[u3];
        int2  t0 = tar2[u0], t1 = tar2[u1], t2 = tar2[u2], t3 = tar2[u3];

        atomicAdd(&ls[s0.x], packexp(a0.x, a0.y));
        atomicAdd(&ls[s0.y], packexp(a0.z, a0.w));
        atomicAdd(&ls[NSEG + t0.x], packexp(b0.x, b0.y));
        atomicAdd(&ls[NSEG + t0.y], packexp(b0.z, b0.w));

        atomicAdd(&ls[s1.x], packexp(a1.x, a1.y));
        atomicAdd(&ls[s1.y], packexp(a1.z, a1.w));
        atomicAdd(&ls[NSEG + t1.x], packexp(b1.x, b1.y));
        atomicAdd(&ls[NSEG + t1.y], packexp(b1.z, b1.w));

        atomicAdd(&ls[s2.x], packexp(a2.x, a2.y));
        atomicAdd(&ls[s2.y], packexp(a2.z, a2.w));
        atomicAdd(&ls[NSEG + t2.x], packexp(b2.x, b2.y));
        atomicAdd(&ls[NSEG + t2.y], packexp(b2.z, b2.w));

        atomicAdd(&ls[s3.x], packexp(a3.x, a3.y));
        atomicAdd(&ls[s3.y], packexp(a3.z, a3.w));
        atomicAdd(&ls[NSEG + t3.x], packexp(b3.x, b3.y));
        atomicAdd(&ls[NSEG + t3.y], packexp(b3.z, b3.w));
    }
    __syncthreads();

    f32x2* dst = (f32x2*)(partials + (size_t)blockIdx.x * (4 * NSEG));
    for (int i = threadIdx.x; i < 2 * NSEG; i += 512) {
        u64 v = ls[i];
        f32x2 w = { (float)(u32)v * QINV, (float)(u32)(v >> 32) * QINV };
        dst[i] = w;
    }
}

// Generic fallback reduce (1024-thr, grid-stride).
__global__ __launch_bounds__(1024) void dsp_reduce_g(
    const f32x4* __restrict__ xab4, const f32x4* __restrict__ xba4,
    const int2* __restrict__ src2, const int2* __restrict__ tar2,
    float* __restrict__ partials, int Eh)
{
    __shared__ u64 ls[2 * NSEG];
    for (int i = threadIdx.x; i < 2 * NSEG; i += 1024) ls[i] = 0ull;
    __syncthreads();

    const int stride = gridDim.x * 1024;
    for (int u = blockIdx.x * 1024 + threadIdx.x; u < Eh; u += stride) {
        f32x4 a = xab4[u]; f32x4 b = xba4[u];
        int2 s = src2[u]; int2 t = tar2[u];
        atomicAdd(&ls[s.x], packexp(a.x, a.y));
        atomicAdd(&ls[s.y], packexp(a.z, a.w));
        atomicAdd(&ls[NSEG + t.x], packexp(b.x, b.y));
        atomicAdd(&ls[NSEG + t.y], packexp(b.z, b.w));
    }
    __syncthreads();

    f32x2* dst = (f32x2*)(partials + (size_t)blockIdx.x * (4 * NSEG));
    for (int i = threadIdx.x; i < 2 * NSEG; i += 1024) {
        u64 v = ls[i];
        f32x2 w = { (float)(u32)v * QINV, (float)(u32)(v >> 32) * QINV };
        dst[i] = w;
    }
}

// ---------------------------------------------------------------------------
// Pass 2: column-sum NB partial tables, store reciprocals.
// ---------------------------------------------------------------------------
__global__ __launch_bounds__(256) void dsp_sum(
    const f32x4* __restrict__ partials, f32x4* __restrict__ rcp_out, int nb)
{
    int i = blockIdx.x * blockDim.x + threadIdx.x;   // 0..4095
    f32x4 acc = {0.f, 0.f, 0.f, 0.f};
    for (int p = 0; p < nb; ++p)
        acc += partials[(size_t)p * NSEG + i];
    f32x4 r;
    r.x = (acc.x > 0.f) ? 1.f / acc.x : 0.f;
    r.y = (acc.y > 0.f) ? 1.f / acc.y : 0.f;
    r.z = (acc.z > 0.f) ? 1.f / acc.z : 0.f;
    r.w = (acc.w > 0.f) ? 1.f / acc.w : 0.f;
    rcp_out[i] = r;
}

// ---------------------------------------------------------------------------
// Pass 3 (exact): normalize + 3 outputs. rcp tables in LDS, 2-deep rotating
// prefetch, NT stores. LDS floats: ab at [0,2*NSEG), ba at [2*NSEG,4*NSEG).
// ---------------------------------------------------------------------------
__global__ __launch_bounds__(1024, 8) void dsp_norm_x(
    const f32x4* __restrict__ xab4, const f32x4* __restrict__ xba4,
    const int2* __restrict__ src2, const int2* __restrict__ tar2,
    const f32x4* __restrict__ rcp_tab,
    f32x4* __restrict__ out, int rounds, int rs, int Eh)
{
    __shared__ float ls[4 * NSEG];
    for (int i = threadIdx.x; i < NSEG; i += 1024)
        ((f32x4*)ls)[i] = rcp_tab[i];
    __syncthreads();

    const int base = blockIdx.x * 1024 + threadIdx.x;

    f32x4 a0 = xab4[base], b0 = xba4[base];
    int2  s0 = src2[base], t0 = tar2[base];
    f32x4 a1, b1; int2 s1, t1;
    if (rounds > 1) {
        int u1 = base + rs;
        a1 = xab4[u1]; b1 = xba4[u1]; s1 = src2[u1]; t1 = tar2[u1];
    }

    for (int r = 0; r < rounds; ++r) {
        int u = base + r * rs;
        int up = u + 2 * rs;
        f32x4 an, bn; int2 sn, tn;
        if (r + 2 < rounds) { an = xab4[up]; bn = xba4[up]; sn = src2[up]; tn = tar2[up]; }

        f32x2 ra0 = *(const f32x2*)&ls[2 * s0.x];
        f32x2 ra1 = *(const f32x2*)&ls[2 * s0.y];
        f32x2 rb0 = *(const f32x2*)&ls[2 * NSEG + 2 * t0.x];
        f32x2 rb1 = *(const f32x2*)&ls[2 * NSEG + 2 * t0.y];

        f32x4 zab = { __expf(a0.x) * ra0.x, __expf(a0.y) * ra0.y,
                      __expf(a0.z) * ra1.x, __expf(a0.w) * ra1.y };
        f32x4 zba = { __expf(b0.x) * rb0.x, __expf(b0.y) * rb0.y,
                      __expf(b0.z) * rb1.x, __expf(b0.w) * rb1.y };
        f32x4 prod = zab * zba;

        __builtin_nontemporal_store(prod, &out[u]);            // zab*zba
        __builtin_nontemporal_store(zab,  &out[Eh + u]);       // zab
        __builtin_nontemporal_store(zba,  &out[2 * Eh + u]);   // zba

        a0 = a1; b0 = b1; s0 = s1; t0 = t1;
        a1 = an; b1 = bn; s1 = sn; t1 = tn;
    }
}

// Generic fallback norm.
__global__ __launch_bounds__(1024) void dsp_norm_g(
    const f32x4* __restrict__ xab4, const f32x4* __restrict__ xba4,
    const int2* __restrict__ src2, const int2* __restrict__ tar2,
    const f32x4* __restrict__ rcp_tab,
    f32x4* __restrict__ out, int Eh)
{
    __shared__ float ls[4 * NSEG];
    for (int i = threadIdx.x; i < NSEG; i += 1024)
        ((f32x4*)ls)[i] = rcp_tab[i];
    __syncthreads();

    const int stride = gridDim.x * 1024;
    for (int u = blockIdx.x * 1024 + threadIdx.x; u < Eh; u += stride) {
        f32x4 a = xab4[u]; f32x4 b = xba4[u];
        int2 s = src2[u]; int2 t = tar2[u];
        f32x2 ra0 = *(const f32x2*)&ls[2 * s.x];
        f32x2 ra1 = *(const f32x2*)&ls[2 * s.y];
        f32x2 rb0 = *(const f32x2*)&ls[2 * NSEG + 2 * t.x];
        f32x2 rb1 = *(const f32x2*)&ls[2 * NSEG + 2 * t.y];
        f32x4 zab = { __expf(a.x) * ra0.x, __expf(a.y) * ra0.y,
                      __expf(a.z) * ra1.x, __expf(a.w) * ra1.y };
        f32x4 zba = { __expf(b.x) * rb0.x, __expf(b.y) * rb0.y,
                      __expf(b.z) * rb1.x, __expf(b.w) * rb1.y };
        f32x4 prod = zab * zba;
        __builtin_nontemporal_store(prod, &out[u]);
        __builtin_nontemporal_store(zab,  &out[Eh + u]);
        __builtin_nontemporal_store(zba,  &out[2 * Eh + u]);
    }
}

extern "C" void kernel_launch(void* const* d_in, const int* in_sizes, int n_in,
                              void* d_out, int out_size, void* d_ws, size_t ws_size,
                              hipStream_t stream)
{
    const int E  = in_sizes[0] / 2;
    const int Eh = E / 2;
    const f32x4* xab4 = (const f32x4*)d_in[0];
    const f32x4* xba4 = (const f32x4*)d_in[1];
    const int2*  src2 = (const int2*)d_in[2];
    const int2*  tar2 = (const int2*)d_in[3];

    float* rcp_tab  = (float*)d_ws;           // 16384 floats
    float* partials = (float*)((char*)d_ws + 65536);
    size_t need = 65536 + (size_t)NB * 65536;

    const int RSTRIDE = NB * 512;             // reduce per-round span
    const int NSPAN   = NB * 1024;            // norm per-round span
    bool exact = (ws_size >= need) &&
                 (Eh % (4 * RSTRIDE) == 0) && (Eh % NSPAN == 0);

    if (exact) {
        int groups = Eh / (4 * RSTRIDE);
        int rounds = Eh / NSPAN;
        dsp_reduce_x<<<NB, 512, 0, stream>>>(xab4, xba4, src2, tar2,
                                             partials, groups, RSTRIDE);
        dsp_sum<<<NSEG / 256, 256, 0, stream>>>((const f32x4*)partials,
                                                (f32x4*)rcp_tab, NB);
        dsp_norm_x<<<NB, 1024, 0, stream>>>(xab4, xba4, src2, tar2,
                                            (const f32x4*)rcp_tab,
                                            (f32x4*)d_out, rounds, NSPAN, Eh);
    } else if (ws_size >= need) {
        dsp_reduce_g<<<NB, 1024, 0, stream>>>(xab4, xba4, src2, tar2,
                                              partials, Eh);
        dsp_sum<<<NSEG / 256, 256, 0, stream>>>((const f32x4*)partials,
                                                (f32x4*)rcp_tab, NB);
        dsp_norm_g<<<NB, 1024, 0, stream>>>(xab4, xba4, src2, tar2,
                                            (const f32x4*)rcp_tab,
                                            (f32x4*)d_out, Eh);
    }
}